// Round 3
// baseline (219.305 us; speedup 1.0000x reference)
//
#include <hip/hip_runtime.h>

#define BATCH 65536
#define TB 32

typedef _Float16 half8 __attribute__((ext_vector_type(8)));
typedef _Float16 half4v __attribute__((ext_vector_type(4)));
typedef _Float16 half2v __attribute__((ext_vector_type(2)));
typedef float fx4 __attribute__((ext_vector_type(4)));

// workspace layout (halves) -- unchanged from R12/R13/R14
#define PW1B_OFF 0        // [4][256][32]  W1 base rows (k<110, pad->128)
#define PW1F_OFF 32768    // [256][32]     W1 feat rows, k-map [feat_i(15) 0 feat_j(15) 0]
#define PW2_OFF  40960    // [8][256][32]
#define PWR_OFF  106496   // [8][256][32]
#define PWH_OFF  172032   // [8][16][32]   [mean_w | lstd_w | pad]
#define WS_TOTAL 176128

__global__ __launch_bounds__(256) void prep_weights(
    const float* __restrict__ w1, const float* __restrict__ w2,
    const float* __restrict__ wr, const float* __restrict__ wm,
    const float* __restrict__ wl, _Float16* __restrict__ ws)
{
  int idx = blockIdx.x * 256 + threadIdx.x;
  if (idx < 32768) {            // pw1b
    int kk = idx & 31, n = (idx >> 5) & 255, kt = idx >> 13;
    int k = kt * 32 + kk;
    ws[idx] = (k < 110) ? (_Float16)w1[k * 256 + n] : (_Float16)0.f;
  } else if (idx < 40960) {     // pw1f
    int t = idx - 32768;
    int kk = t & 31, n = t >> 5;
    _Float16 v = (_Float16)0.f;
    if (kk < 15)                  v = (_Float16)w1[(113 + kk) * 256 + n];
    else if (kk >= 16 && kk < 31) v = (_Float16)w1[(131 + (kk - 16)) * 256 + n];
    ws[idx] = v;
  } else if (idx < 106496) {    // pw2
    int t = idx - 40960;
    int kk = t & 31, n = (t >> 5) & 255, kt = t >> 13;
    ws[idx] = (_Float16)w2[(kt * 32 + kk) * 256 + n];
  } else if (idx < 172032) {    // pwr
    int t = idx - 106496;
    int kk = t & 31, n = (t >> 5) & 255, kt = t >> 13;
    ws[idx] = (_Float16)wr[(kt * 32 + kk) * 256 + n];
  } else if (idx < WS_TOTAL) {  // pwh
    int t = idx - 172032;
    int kk = t & 31, n = (t >> 5) & 15, kt = t >> 9;
    int k = kt * 32 + kk;
    _Float16 v = (_Float16)0.f;
    if (n < 4) v = (_Float16)wm[k * 4 + n];
    else if (n < 8) v = (_Float16)wl[k * 4 + (n - 4)];
    ws[PWH_OFF + t] = v;
  }
}

// R15: the allocator is empirically pinned at 64 VGPRs (R13/R14: VGPR_Count=64
// regardless of launch-bounds/waves_per_eu; R14 spilled 200MB of scratch).
// So: make the working set FIT 64.
//  - 3 phases of 2 perms: acc[8] (32 regs) instead of acc[12] (48).
//    H1 shrinks 48->32KB, LDS 57KB -> still 2 blocks/CU.
//  - u recomputed per phase (never live across a g2 loop); recompute issued
//    before the pre-g1 barrier so it overlaps other waves' g2 tail.
//  - agg carried PACKED fp16 (8 regs, not 16) between g2 epilogues.
//  - g2 keeps in-loop A reads (no a[6] batch: that's what blew up R14).
//  - conflict-free wave-contiguous staging kept from R14 (3.1M->2.1M cycles).
// g2 peak live: acc32 + aggp8 + bb8 + a4 + addrs ~ 58 < 64 -> no spill.
__global__ __launch_bounds__(512) void actor_fused(
    const float* __restrict__ obs, const float* __restrict__ lemb,
    const float* __restrict__ w1, const _Float16* __restrict__ ws,
    const float* __restrict__ b1, const float* __restrict__ b2,
    const float* __restrict__ br, const float* __restrict__ bm,
    const float* __restrict__ bl, float* __restrict__ out)
{
  __shared__ __align__(16) _Float16 H1[4 * 16 * 256]; // 32 KB: 4 tiles (pp*2+rt); tiles 0,1 later r
  __shared__ __align__(16) _Float16 Bb[32 * 256];     // 16 KB: base (K=128), later agg (K=256)
  __shared__ __align__(16) _Float16 Os[3 * 32 * 16];  //  3 KB: compact obj tiles
  __shared__ __align__(16) float    Bsf[6 * 256];     //  6 KB: fused per-perm biases (f32)

  const _Float16* __restrict__ pw1b = ws + PW1B_OFF;
  const _Float16* __restrict__ pw1f = ws + PW1F_OFF;
  const _Float16* __restrict__ pw2  = ws + PW2_OFF;
  const _Float16* __restrict__ pwr  = ws + PWR_OFF;
  const _Float16* __restrict__ pwh  = ws + PWH_OFF;

  const int tid  = threadIdx.x;
  const int wave = tid >> 6;        // 0..7
  const int lane = tid & 63;
  const int q    = lane >> 4;
  const int l16  = lane & 15;
  const int colbase = wave * 32;    // this wave's 32 output cols
  const int rowbase = blockIdx.x * TB;

  const int c0_0 = colbase + q * 4;        // start col of this lane's 4-col pack, nt=0
  const int c0_1 = colbase + 16 + q * 4;   // nt=1

  // ---- stage base (32 rows x K=128) -- wave-contiguous: lane i writes 8B at
  // chunk_base + i*8 within one 512B k-octet chunk -> conflict-free ----
  for (int idx = tid; idx < 1024; idx += 512) {
    int oct = idx >> 6;          // 0..15 (= k-octet)
    int r   = (idx >> 1) & 31;   // row
    int hf  = idx & 1;           // which 4-col half of the octet
    int c   = oct * 8 + hf * 4;
    float v0, v1, v2, v3;
    if (c + 3 < 100) {
      float4 f = *(const float4*)(lemb + (rowbase + r) * 100 + c);
      v0 = f.x; v1 = f.y; v2 = f.z; v3 = f.w;
    } else {
      const float* orow = obs + (rowbase + r) * 55;
      const float* lrow = lemb + (rowbase + r) * 100;
      float t[4];
      #pragma unroll
      for (int j = 0; j < 4; ++j) {
        int cc = c + j;
        t[j] = cc < 100 ? lrow[cc] : (cc < 110 ? orow[cc - 100] : 0.f);
      }
      v0 = t[0]; v1 = t[1]; v2 = t[2]; v3 = t[3];
    }
    half4v hv = {(_Float16)v0, (_Float16)v1, (_Float16)v2, (_Float16)v3};
    *(half4v*)&Bb[(oct * 32 + r) * 8 + hf * 4] = hv;
  }
  // ---- compact obj tiles: 3 obj x 2 k-octets x 32 rows, 8B per lane ----
  for (int idx = tid; idx < 384; idx += 512) {
    int o   = idx >> 7;          // 0..2
    int k4i = (idx >> 5) & 3;    // which 4-k group
    int r   = idx & 31;
    int k0  = k4i * 4;
    const float* frow = obs + (rowbase + r) * 55 + 10 + o * 15;
    float t[4];
    #pragma unroll
    for (int j = 0; j < 4; ++j) {
      int k = k0 + j;
      t[j] = (k < 15) ? frow[k] : 0.f;
    }
    half4v hv = {(_Float16)t[0], (_Float16)t[1], (_Float16)t[2], (_Float16)t[3]};
    *(half4v*)&Os[o * 512 + ((k0 >> 3) * 32 + r) * 8 + (k0 & 7)] = hv;
  }
  // ---- fused per-perm biases (f32): b1 + W1[onehot_i row] + W1[onehot_j row] ----
  for (int idx = tid; idx < 1536; idx += 512) {
    int p = idx >> 8, c = idx & 255;
    int oi = p >> 1, oj = (1161 >> (2 * p)) & 3;
    Bsf[idx] = b1[c] + w1[(110 + oi) * 256 + c] + w1[(128 + oj) * 256 + c];
  }
  __syncthreads();  // B1

  const fx4 zero4 = {0.f, 0.f, 0.f, 0.f};

  // ---- U = (base @ W1base)^T (K=128); cheap enough to recompute per phase ----
  auto compute_u = [&](fx4* u) {
    u[0] = zero4; u[1] = zero4; u[2] = zero4; u[3] = zero4;
    #pragma unroll
    for (int kt = 0; kt < 4; ++kt) {
      half8 a0 = *(const half8*)&Bb[((kt * 4 + q) * 32 + l16) * 8];
      half8 a1 = *(const half8*)&Bb[((kt * 4 + q) * 32 + 16 + l16) * 8];
      #pragma unroll
      for (int nt = 0; nt < 2; ++nt) {
        half8 b = *(const half8*)&pw1b[(kt * 256 + colbase + nt * 16 + l16) * 32 + q * 8];
        u[nt]     = __builtin_amdgcn_mfma_f32_16x16x32_f16(b, a0, u[nt], 0, 0, 0);
        u[2 + nt] = __builtin_amdgcn_mfma_f32_16x16x32_f16(b, a1, u[2 + nt], 0, 0, 0);
      }
    }
  };

  // ---- GEMM1 pair: h1_p = relu(U + F_p @ W1f + bias_p), perms {2g, 2g+1} ----
  auto g1_pair = [&](int g, const fx4* u) {
    half8 b1f0 = *(const half8*)&pw1f[(colbase + l16) * 32 + q * 8];
    half8 b1f1 = *(const half8*)&pw1f[(colbase + 16 + l16) * 32 + q * 8];
    #pragma unroll
    for (int pp = 0; pp < 2; ++pp) {
      const int p = g * 2 + pp;
      const int oi = p >> 1, oj = (1161 >> (2 * p)) & 3;
      const int o = (q < 2) ? oi : oj;   // quads 0,1 -> feat_i; 2,3 -> feat_j
      #pragma unroll
      for (int rt = 0; rt < 2; ++rt) {
        half8 af = *(const half8*)&Os[o * 512 + ((q & 1) * 32 + rt * 16 + l16) * 8];
        #pragma unroll
        for (int nt = 0; nt < 2; ++nt) {
          fx4 t = __builtin_amdgcn_mfma_f32_16x16x32_f16(nt ? b1f1 : b1f0, af,
                                                         u[rt * 2 + nt], 0, 0, 0);
          const int c0 = nt ? c0_1 : c0_0;
          fx4 bs = *(const fx4*)&Bsf[p * 256 + c0];
          half4v hv = {(_Float16)fmaxf(t[0] + bs[0], 0.f),
                       (_Float16)fmaxf(t[1] + bs[1], 0.f),
                       (_Float16)fmaxf(t[2] + bs[2], 0.f),
                       (_Float16)fmaxf(t[3] + bs[3], 0.f)};
          *(half4v*)&H1[(pp * 2 + rt) * 4096 + ((c0 >> 3) * 16 + l16) * 8 + (c0 & 7)] = hv;
        }
      }
    }
  };

  // ---- running agg, packed fp16 (8 VGPRs): aggp[rt*2+nt] ----
  half4v aggp[4];
  {
    half4v z = {(_Float16)0.f, (_Float16)0.f, (_Float16)0.f, (_Float16)0.f};
    aggp[0] = z; aggp[1] = z; aggp[2] = z; aggp[3] = z;
  }

  // ---- GEMM2 pair: 4 tiles (2p x 2rt), K=256, bias-folded init ----
  auto g2_pair = [&]() {
    fx4 bv0 = *(const fx4*)&b2[c0_0];
    fx4 bv1 = *(const fx4*)&b2[c0_1];
    fx4 acc[8];
    #pragma unroll
    for (int i = 0; i < 8; ++i) acc[i] = (i & 1) ? bv1 : bv0;
    #pragma unroll 2
    for (int kt = 0; kt < 8; ++kt) {
      half8 bb0 = *(const half8*)&pw2[(kt * 256 + colbase + l16) * 32 + q * 8];
      half8 bb1 = *(const half8*)&pw2[(kt * 256 + colbase + 16 + l16) * 32 + q * 8];
      #pragma unroll
      for (int t4 = 0; t4 < 4; ++t4) {
        half8 a = *(const half8*)&H1[t4 * 4096 + ((kt * 4 + q) * 16 + l16) * 8];
        acc[t4 * 2]     = __builtin_amdgcn_mfma_f32_16x16x32_f16(bb0, a, acc[t4 * 2], 0, 0, 0);
        acc[t4 * 2 + 1] = __builtin_amdgcn_mfma_f32_16x16x32_f16(bb1, a, acc[t4 * 2 + 1], 0, 0, 0);
      }
    }
    // epilogue: unpack agg, add relu(acc) of both perms, repack
    #pragma unroll
    for (int rt = 0; rt < 2; ++rt)
      #pragma unroll
      for (int nt = 0; nt < 2; ++nt) {
        int i = rt * 2 + nt;
        fx4 s;
        #pragma unroll
        for (int rr = 0; rr < 4; ++rr) s[rr] = (float)aggp[i][rr];
        #pragma unroll
        for (int rr = 0; rr < 4; ++rr) {
          s[rr] += fmaxf(acc[rt * 2 + nt][rr], 0.f);           // perm 2g
          s[rr] += fmaxf(acc[(2 + rt) * 2 + nt][rr], 0.f);     // perm 2g+1
        }
        half4v hv = {(_Float16)s[0], (_Float16)s[1], (_Float16)s[2], (_Float16)s[3]};
        aggp[i] = hv;
      }
  };

  // ---- phase loop: 3 x (u, g1 pair, g2 pair) ----
  {
    fx4 u[4];
    compute_u(u);
    g1_pair(0, u);
    __syncthreads();  // B2: h1 perms 0,1 ready
    g2_pair();
    compute_u(u);     // overlaps other waves' g2 tail (touches only Bb, stable)
    __syncthreads();  // B3: all H1 reads done
    g1_pair(1, u);
    __syncthreads();  // B4
    g2_pair();
    compute_u(u);
    __syncthreads();  // B5
    g1_pair(2, u);
    __syncthreads();  // B6
    g2_pair();
  }

  // stage agg into Bb (base region dead: last compute_u long past for all
  // waves -- they are past B6 and their own g2) -- already fp16, direct store
  #pragma unroll
  for (int rt = 0; rt < 2; ++rt)
    #pragma unroll
    for (int nt = 0; nt < 2; ++nt) {
      const int c0 = nt ? c0_1 : c0_0;
      *(half4v*)&Bb[((c0 >> 3) * 32 + rt * 16 + l16) * 8 + (c0 & 7)] = aggp[rt * 2 + nt];
    }
  __syncthreads();  // B7: agg complete in Bb; all H1 reads done

  // ---- GEMM3: r = relu(agg @ rho + br), M=32, K=256; r -> H1 tiles 0,1 ----
  fx4 acc3[4];  // [rt*2+nt]
  {
    fx4 brv0 = *(const fx4*)&br[c0_0];
    fx4 brv1 = *(const fx4*)&br[c0_1];
    acc3[0] = brv0; acc3[1] = brv1; acc3[2] = brv0; acc3[3] = brv1;
  }
  #pragma unroll 2
  for (int kt = 0; kt < 8; ++kt) {
    half8 a0 = *(const half8*)&Bb[((kt * 4 + q) * 32 + l16) * 8];
    half8 a1 = *(const half8*)&Bb[((kt * 4 + q) * 32 + 16 + l16) * 8];
    half8 b0 = *(const half8*)&pwr[(kt * 256 + colbase + l16) * 32 + q * 8];
    half8 b1h = *(const half8*)&pwr[(kt * 256 + colbase + 16 + l16) * 32 + q * 8];
    acc3[0] = __builtin_amdgcn_mfma_f32_16x16x32_f16(b0,  a0, acc3[0], 0, 0, 0);
    acc3[1] = __builtin_amdgcn_mfma_f32_16x16x32_f16(b1h, a0, acc3[1], 0, 0, 0);
    acc3[2] = __builtin_amdgcn_mfma_f32_16x16x32_f16(b0,  a1, acc3[2], 0, 0, 0);
    acc3[3] = __builtin_amdgcn_mfma_f32_16x16x32_f16(b1h, a1, acc3[3], 0, 0, 0);
  }
  #pragma unroll
  for (int rt = 0; rt < 2; ++rt)
    #pragma unroll
    for (int nt = 0; nt < 2; ++nt) {
      const int c0 = nt ? c0_1 : c0_0;
      fx4 t = acc3[rt * 2 + nt];
      half4v hv = {(_Float16)fmaxf(t[0], 0.f), (_Float16)fmaxf(t[1], 0.f),
                   (_Float16)fmaxf(t[2], 0.f), (_Float16)fmaxf(t[3], 0.f)};
      *(half4v*)&H1[rt * 4096 + ((c0 >> 3) * 16 + l16) * 8 + (c0 & 7)] = hv;
    }
  __syncthreads();  // B8: r ready

  // ---- heads: waves 0,1 (one row-half each); swapped D -> float4 stores ----
  if (wave < 2) {
    fx4 a4 = zero4;
    #pragma unroll 2
    for (int kt = 0; kt < 8; ++kt) {
      half8 rfrag = *(const half8*)&H1[wave * 4096 + ((kt * 4 + q) * 16 + l16) * 8];
      half8 wfrag = *(const half8*)&pwh[(kt * 16 + l16) * 32 + q * 8];
      a4 = __builtin_amdgcn_mfma_f32_16x16x32_f16(wfrag, rfrag, a4, 0, 0, 0);
    }
    const int row = rowbase + wave * 16 + l16;
    if (q == 0) {            // head cols 0..3 = mean
      fx4 bm4 = *(const fx4*)bm;
      fx4 o = {a4[0] + bm4[0], a4[1] + bm4[1], a4[2] + bm4[2], a4[3] + bm4[3]};
      *(fx4*)&out[row * 4] = o;
    } else if (q == 1) {     // head cols 4..7 = log_std (clipped)
      fx4 bl4 = *(const fx4*)bl;
      fx4 o;
      #pragma unroll
      for (int rr = 0; rr < 4; ++rr) {
        float v = a4[rr] + bl4[rr];
        o[rr] = v < -20.f ? -20.f : (v > 2.f ? 2.f : v);
      }
      *(fx4*)&out[BATCH * 4 + row * 4] = o;
    }
  }
}

extern "C" void kernel_launch(void* const* d_in, const int* in_sizes, int n_in,
                              void* d_out, int out_size, void* d_ws, size_t ws_size,
                              hipStream_t stream) {
  const float* obs  = (const float*)d_in[0];
  const float* lemb = (const float*)d_in[1];
  const float* w1   = (const float*)d_in[2];
  const float* b1   = (const float*)d_in[3];
  const float* w2   = (const float*)d_in[4];
  const float* b2   = (const float*)d_in[5];
  const float* wr   = (const float*)d_in[6];
  const float* br   = (const float*)d_in[7];
  const float* wm   = (const float*)d_in[8];
  const float* bm   = (const float*)d_in[9];
  const float* wl   = (const float*)d_in[10];
  const float* bl   = (const float*)d_in[11];
  float* out = (float*)d_out;
  _Float16* ws = (_Float16*)d_ws;

  hipLaunchKernelGGL(prep_weights, dim3(WS_TOTAL / 256), dim3(256), 0, stream,
                     w1, w2, wr, wm, wl, ws);
  hipLaunchKernelGGL(actor_fused, dim3(BATCH / TB), dim3(512), 0, stream,
                     obs, lemb, w1, (const _Float16*)ws, b1, b2, br, bm, bl, out);
}

// Round 4
// 215.860 us; speedup vs baseline: 1.0160x; 1.0160x over previous
//
#include <hip/hip_runtime.h>

#define BATCH 65536
#define TB 32

typedef _Float16 half8 __attribute__((ext_vector_type(8)));
typedef _Float16 half4v __attribute__((ext_vector_type(4)));
typedef _Float16 half2v __attribute__((ext_vector_type(2)));
typedef float fx4 __attribute__((ext_vector_type(4)));

// workspace layout (halves) -- unchanged from R12..R15
#define PW1B_OFF 0        // [4][256][32]  W1 base rows (k<110, pad->128)
#define PW1F_OFF 32768    // [256][32]     W1 feat rows, k-map [feat_i(15) 0 feat_j(15) 0]
#define PW2_OFF  40960    // [8][256][32]
#define PWR_OFF  106496   // [8][256][32]
#define PWH_OFF  172032   // [8][16][32]   [mean_w | lstd_w | pad]
#define WS_TOTAL 176128

__global__ __launch_bounds__(256) void prep_weights(
    const float* __restrict__ w1, const float* __restrict__ w2,
    const float* __restrict__ wr, const float* __restrict__ wm,
    const float* __restrict__ wl, _Float16* __restrict__ ws)
{
  int idx = blockIdx.x * 256 + threadIdx.x;
  if (idx < 32768) {            // pw1b
    int kk = idx & 31, n = (idx >> 5) & 255, kt = idx >> 13;
    int k = kt * 32 + kk;
    ws[idx] = (k < 110) ? (_Float16)w1[k * 256 + n] : (_Float16)0.f;
  } else if (idx < 40960) {     // pw1f
    int t = idx - 32768;
    int kk = t & 31, n = t >> 5;
    _Float16 v = (_Float16)0.f;
    if (kk < 15)                  v = (_Float16)w1[(113 + kk) * 256 + n];
    else if (kk >= 16 && kk < 31) v = (_Float16)w1[(131 + (kk - 16)) * 256 + n];
    ws[idx] = v;
  } else if (idx < 106496) {    // pw2
    int t = idx - 40960;
    int kk = t & 31, n = (t >> 5) & 255, kt = t >> 13;
    ws[idx] = (_Float16)w2[(kt * 32 + kk) * 256 + n];
  } else if (idx < 172032) {    // pwr
    int t = idx - 106496;
    int kk = t & 31, n = (t >> 5) & 255, kt = t >> 13;
    ws[idx] = (_Float16)wr[(kt * 32 + kk) * 256 + n];
  } else if (idx < WS_TOTAL) {  // pwh
    int t = idx - 172032;
    int kk = t & 31, n = (t >> 5) & 15, kt = t >> 9;
    int k = kt * 32 + kk;
    _Float16 v = (_Float16)0.f;
    if (n < 4) v = (_Float16)wm[k * 4 + n];
    else if (n < 8) v = (_Float16)wl[k * 4 + (n - 4)];
    ws[PWH_OFF + t] = v;
  }
}

// R16 = R13 (best, 117us) with its spill removed.
// Model established over R13-R15: allocator picks an occupancy tier from its
// own pressure estimate (caps only bind from above); occupancy needs TOTAL
// (arch+accum) <= 128 for 2 blocks/CU (4 waves/SIMD x 128 = 512).
//  - R13: acc[12]+u live = ~112 total but allocator chose 64-tier -> 12MB spill.
//  - R15: 3-phase fit arch=84 but total ~132 > 128 -> 1 block/CU, occ 23%, slow.
// R16: 2x3-perm phases (R13 structure, 6 barriers, u computed ONCE and held),
// but g2 is nt-SPLIT: two sequential passes with acc[6] (24 AGPR) instead of
// acc[12] (48). Same MFMA count, same pw2 traffic; only cost is re-reading H1
// A-fragments per pass (LDS pipe, overlappable). Peak live ~80-95 -> no spill,
// total <= 128 -> 2 blocks/CU. agg stays f32 (numerics identical to R13).
// Staging is R14's conflict-free wave-contiguous variant (3.1M->2.1M cycles).
__global__ __launch_bounds__(512) void actor_fused(
    const float* __restrict__ obs, const float* __restrict__ lemb,
    const float* __restrict__ w1, const _Float16* __restrict__ ws,
    const float* __restrict__ b1, const float* __restrict__ b2,
    const float* __restrict__ br, const float* __restrict__ bm,
    const float* __restrict__ bl, float* __restrict__ out)
{
  __shared__ __align__(16) _Float16 H1[6 * 16 * 256]; // 48 KB: 6 tiles (pp*2+rt); tiles 0,1 later r
  __shared__ __align__(16) _Float16 Bb[32 * 256];     // 16 KB: base (K=128), later agg (K=256)
  __shared__ __align__(16) _Float16 Os[3 * 32 * 16];  //  3 KB: compact obj tiles
  __shared__ __align__(16) float    Bsf[6 * 256];     //  6 KB: fused per-perm biases (f32)

  const _Float16* __restrict__ pw1b = ws + PW1B_OFF;
  const _Float16* __restrict__ pw1f = ws + PW1F_OFF;
  const _Float16* __restrict__ pw2  = ws + PW2_OFF;
  const _Float16* __restrict__ pwr  = ws + PWR_OFF;
  const _Float16* __restrict__ pwh  = ws + PWH_OFF;

  const int tid  = threadIdx.x;
  const int wave = tid >> 6;        // 0..7
  const int lane = tid & 63;
  const int q    = lane >> 4;
  const int l16  = lane & 15;
  const int colbase = wave * 32;    // this wave's 32 output cols
  const int rowbase = blockIdx.x * TB;

  const int c0_0 = colbase + q * 4;        // start col of this lane's 4-col pack, nt=0
  const int c0_1 = colbase + 16 + q * 4;   // nt=1

  // ---- stage base (32 rows x K=128) -- wave-contiguous: lane i writes 8B at
  // chunk_base + i*8 within one 512B k-octet chunk -> conflict-free ----
  for (int idx = tid; idx < 1024; idx += 512) {
    int oct = idx >> 6;          // 0..15 (= k-octet)
    int r   = (idx >> 1) & 31;   // row
    int hf  = idx & 1;           // which 4-col half of the octet
    int c   = oct * 8 + hf * 4;
    float v0, v1, v2, v3;
    if (c + 3 < 100) {
      float4 f = *(const float4*)(lemb + (rowbase + r) * 100 + c);
      v0 = f.x; v1 = f.y; v2 = f.z; v3 = f.w;
    } else {
      const float* orow = obs + (rowbase + r) * 55;
      const float* lrow = lemb + (rowbase + r) * 100;
      float t[4];
      #pragma unroll
      for (int j = 0; j < 4; ++j) {
        int cc = c + j;
        t[j] = cc < 100 ? lrow[cc] : (cc < 110 ? orow[cc - 100] : 0.f);
      }
      v0 = t[0]; v1 = t[1]; v2 = t[2]; v3 = t[3];
    }
    half4v hv = {(_Float16)v0, (_Float16)v1, (_Float16)v2, (_Float16)v3};
    *(half4v*)&Bb[(oct * 32 + r) * 8 + hf * 4] = hv;
  }
  // ---- compact obj tiles: 3 obj x 2 k-octets x 32 rows, 8B per lane ----
  for (int idx = tid; idx < 384; idx += 512) {
    int o   = idx >> 7;          // 0..2
    int k4i = (idx >> 5) & 3;    // which 4-k group
    int r   = idx & 31;
    int k0  = k4i * 4;
    const float* frow = obs + (rowbase + r) * 55 + 10 + o * 15;
    float t[4];
    #pragma unroll
    for (int j = 0; j < 4; ++j) {
      int k = k0 + j;
      t[j] = (k < 15) ? frow[k] : 0.f;
    }
    half4v hv = {(_Float16)t[0], (_Float16)t[1], (_Float16)t[2], (_Float16)t[3]};
    *(half4v*)&Os[o * 512 + ((k0 >> 3) * 32 + r) * 8 + (k0 & 7)] = hv;
  }
  // ---- fused per-perm biases (f32): b1 + W1[onehot_i row] + W1[onehot_j row] ----
  for (int idx = tid; idx < 1536; idx += 512) {
    int p = idx >> 8, c = idx & 255;
    int oi = p >> 1, oj = (1161 >> (2 * p)) & 3;
    Bsf[idx] = b1[c] + w1[(110 + oi) * 256 + c] + w1[(128 + oj) * 256 + c];
  }
  __syncthreads();  // B1

  const fx4 zero4 = {0.f, 0.f, 0.f, 0.f};

  // ---- U = (base @ W1base)^T tiles (K=128), computed ONCE, held in regs ----
  fx4 u[4];  // [rt*2+nt]
  u[0] = zero4; u[1] = zero4; u[2] = zero4; u[3] = zero4;
  #pragma unroll
  for (int kt = 0; kt < 4; ++kt) {
    half8 a0 = *(const half8*)&Bb[((kt * 4 + q) * 32 + l16) * 8];
    half8 a1 = *(const half8*)&Bb[((kt * 4 + q) * 32 + 16 + l16) * 8];
    #pragma unroll
    for (int nt = 0; nt < 2; ++nt) {
      half8 b = *(const half8*)&pw1b[(kt * 256 + colbase + nt * 16 + l16) * 32 + q * 8];
      u[nt]     = __builtin_amdgcn_mfma_f32_16x16x32_f16(b, a0, u[nt], 0, 0, 0);
      u[2 + nt] = __builtin_amdgcn_mfma_f32_16x16x32_f16(b, a1, u[2 + nt], 0, 0, 0);
    }
  }
  // no barrier: Bb not rewritten until the agg store; H1 unread so far

  // ---- GEMM1 group: h1_p = relu(U + F_p @ W1f + bias_p), perms {3g..3g+2} ----
  // swapped D: lane holds row l16 (batch), cols c0..c0+3 -> packed b64 store
  auto g1_group = [&](int g) {
    half8 b1f0 = *(const half8*)&pw1f[(colbase + l16) * 32 + q * 8];
    half8 b1f1 = *(const half8*)&pw1f[(colbase + 16 + l16) * 32 + q * 8];
    #pragma unroll
    for (int pp = 0; pp < 3; ++pp) {
      const int p = g * 3 + pp;
      const int oi = p >> 1, oj = (1161 >> (2 * p)) & 3;
      const int o = (q < 2) ? oi : oj;   // quads 0,1 -> feat_i; 2,3 -> feat_j
      #pragma unroll
      for (int rt = 0; rt < 2; ++rt) {
        half8 af = *(const half8*)&Os[o * 512 + ((q & 1) * 32 + rt * 16 + l16) * 8];
        #pragma unroll
        for (int nt = 0; nt < 2; ++nt) {
          fx4 t = __builtin_amdgcn_mfma_f32_16x16x32_f16(nt ? b1f1 : b1f0, af,
                                                         u[rt * 2 + nt], 0, 0, 0);
          const int c0 = nt ? c0_1 : c0_0;
          fx4 bs = *(const fx4*)&Bsf[p * 256 + c0];
          half4v hv = {(_Float16)fmaxf(t[0] + bs[0], 0.f),
                       (_Float16)fmaxf(t[1] + bs[1], 0.f),
                       (_Float16)fmaxf(t[2] + bs[2], 0.f),
                       (_Float16)fmaxf(t[3] + bs[3], 0.f)};
          *(half4v*)&H1[(pp * 2 + rt) * 4096 + ((c0 >> 3) * 16 + l16) * 8 + (c0 & 7)] = hv;
        }
      }
    }
  };

  // ---- running agg in f32 (numerics identical to R13) ----
  fx4 agg[4];  // [rt*2+nt]
  agg[0] = zero4; agg[1] = zero4; agg[2] = zero4; agg[3] = zero4;

  // ---- GEMM2 group: 6 tiles (3p x 2rt), K=256, nt-SPLIT into two passes.
  // acc[6] = 24 AGPR per pass (vs 48 in R13 -> this is the spill fix).
  // Same MFMA count and same pw2 traffic; H1 A-frags re-read per pass (LDS).
  auto g2_group = [&]() {
    #pragma unroll
    for (int nt = 0; nt < 2; ++nt) {
      const int c0 = nt ? c0_1 : c0_0;
      fx4 bv = *(const fx4*)&b2[c0];
      fx4 acc[6];  // [pp*2+rt]
      #pragma unroll
      for (int i = 0; i < 6; ++i) acc[i] = bv;
      #pragma unroll 2
      for (int kt = 0; kt < 8; ++kt) {
        half8 bb = *(const half8*)&pw2[(kt * 256 + colbase + nt * 16 + l16) * 32 + q * 8];
        #pragma unroll
        for (int t6 = 0; t6 < 6; ++t6) {
          half8 a = *(const half8*)&H1[t6 * 4096 + ((kt * 4 + q) * 16 + l16) * 8];
          acc[t6] = __builtin_amdgcn_mfma_f32_16x16x32_f16(bb, a, acc[t6], 0, 0, 0);
        }
      }
      #pragma unroll
      for (int t6 = 0; t6 < 6; ++t6)
        #pragma unroll
        for (int rr = 0; rr < 4; ++rr)
          agg[(t6 & 1) * 2 + nt][rr] += fmaxf(acc[t6][rr], 0.f);  // t6&1 = rt
    }
  };

  g1_group(0);
  __syncthreads();  // B2: h1 perms 0-2 ready
  g2_group();
  __syncthreads();  // B3: all H1 reads of group 0 done
  g1_group(1);
  __syncthreads();  // B4: h1 perms 3-5 ready
  g2_group();

  // stage agg into Bb (base region dead: U long past for all waves -- they are
  // past B4 and their own g2) -- no barrier needed before the store
  #pragma unroll
  for (int rt = 0; rt < 2; ++rt)
    #pragma unroll
    for (int nt = 0; nt < 2; ++nt) {
      const int c0 = nt ? c0_1 : c0_0;
      fx4 t = agg[rt * 2 + nt];
      half4v hv = {(_Float16)t[0], (_Float16)t[1], (_Float16)t[2], (_Float16)t[3]};
      *(half4v*)&Bb[((c0 >> 3) * 32 + rt * 16 + l16) * 8 + (c0 & 7)] = hv;
    }
  __syncthreads();  // B5: agg complete in Bb; all H1 reads done

  // ---- GEMM3: r = relu(agg @ rho + br), M=32, K=256; r -> H1 tiles 0,1 ----
  fx4 acc3[4];  // [rt*2+nt]
  {
    fx4 brv0 = *(const fx4*)&br[c0_0];
    fx4 brv1 = *(const fx4*)&br[c0_1];
    acc3[0] = brv0; acc3[1] = brv1; acc3[2] = brv0; acc3[3] = brv1;
  }
  #pragma unroll 2
  for (int kt = 0; kt < 8; ++kt) {
    half8 a0 = *(const half8*)&Bb[((kt * 4 + q) * 32 + l16) * 8];
    half8 a1 = *(const half8*)&Bb[((kt * 4 + q) * 32 + 16 + l16) * 8];
    half8 b0 = *(const half8*)&pwr[(kt * 256 + colbase + l16) * 32 + q * 8];
    half8 b1h = *(const half8*)&pwr[(kt * 256 + colbase + 16 + l16) * 32 + q * 8];
    acc3[0] = __builtin_amdgcn_mfma_f32_16x16x32_f16(b0,  a0, acc3[0], 0, 0, 0);
    acc3[1] = __builtin_amdgcn_mfma_f32_16x16x32_f16(b1h, a0, acc3[1], 0, 0, 0);
    acc3[2] = __builtin_amdgcn_mfma_f32_16x16x32_f16(b0,  a1, acc3[2], 0, 0, 0);
    acc3[3] = __builtin_amdgcn_mfma_f32_16x16x32_f16(b1h, a1, acc3[3], 0, 0, 0);
  }
  #pragma unroll
  for (int rt = 0; rt < 2; ++rt)
    #pragma unroll
    for (int nt = 0; nt < 2; ++nt) {
      const int c0 = nt ? c0_1 : c0_0;
      fx4 t = acc3[rt * 2 + nt];
      half4v hv = {(_Float16)fmaxf(t[0], 0.f), (_Float16)fmaxf(t[1], 0.f),
                   (_Float16)fmaxf(t[2], 0.f), (_Float16)fmaxf(t[3], 0.f)};
      *(half4v*)&H1[rt * 4096 + ((c0 >> 3) * 16 + l16) * 8 + (c0 & 7)] = hv;
    }
  __syncthreads();  // B6: r ready

  // ---- heads: waves 0,1 (one row-half each); swapped D -> float4 stores ----
  if (wave < 2) {
    fx4 a4 = zero4;
    #pragma unroll 2
    for (int kt = 0; kt < 8; ++kt) {
      half8 rfrag = *(const half8*)&H1[wave * 4096 + ((kt * 4 + q) * 16 + l16) * 8];
      half8 wfrag = *(const half8*)&pwh[(kt * 16 + l16) * 32 + q * 8];
      a4 = __builtin_amdgcn_mfma_f32_16x16x32_f16(wfrag, rfrag, a4, 0, 0, 0);
    }
    const int row = rowbase + wave * 16 + l16;
    if (q == 0) {            // head cols 0..3 = mean
      fx4 bm4 = *(const fx4*)bm;
      fx4 o = {a4[0] + bm4[0], a4[1] + bm4[1], a4[2] + bm4[2], a4[3] + bm4[3]};
      *(fx4*)&out[row * 4] = o;
    } else if (q == 1) {     // head cols 4..7 = log_std (clipped)
      fx4 bl4 = *(const fx4*)bl;
      fx4 o;
      #pragma unroll
      for (int rr = 0; rr < 4; ++rr) {
        float v = a4[rr] + bl4[rr];
        o[rr] = v < -20.f ? -20.f : (v > 2.f ? 2.f : v);
      }
      *(fx4*)&out[BATCH * 4 + row * 4] = o;
    }
  }
}

extern "C" void kernel_launch(void* const* d_in, const int* in_sizes, int n_in,
                              void* d_out, int out_size, void* d_ws, size_t ws_size,
                              hipStream_t stream) {
  const float* obs  = (const float*)d_in[0];
  const float* lemb = (const float*)d_in[1];
  const float* w1   = (const float*)d_in[2];
  const float* b1   = (const float*)d_in[3];
  const float* w2   = (const float*)d_in[4];
  const float* b2   = (const float*)d_in[5];
  const float* wr   = (const float*)d_in[6];
  const float* br   = (const float*)d_in[7];
  const float* wm   = (const float*)d_in[8];
  const float* bm   = (const float*)d_in[9];
  const float* wl   = (const float*)d_in[10];
  const float* bl   = (const float*)d_in[11];
  float* out = (float*)d_out;
  _Float16* ws = (_Float16*)d_ws;

  hipLaunchKernelGGL(prep_weights, dim3(WS_TOTAL / 256), dim3(256), 0, stream,
                     w1, w2, wr, wm, wl, ws);
  hipLaunchKernelGGL(actor_fused, dim3(BATCH / TB), dim3(512), 0, stream,
                     obs, lemb, w1, (const _Float16*)ws, b1, b2, br, bm, bl, out);
}

// Round 5
// 193.935 us; speedup vs baseline: 1.1308x; 1.1131x over previous
//
#include <hip/hip_runtime.h>

#define BATCH 65536
#define TB 32

typedef _Float16 half8 __attribute__((ext_vector_type(8)));
typedef _Float16 half4v __attribute__((ext_vector_type(4)));
typedef _Float16 half2v __attribute__((ext_vector_type(2)));
typedef float fx4 __attribute__((ext_vector_type(4)));

// workspace layout (halves) -- unchanged from R12..R16
#define PW1B_OFF 0        // [4][256][32]  W1 base rows (k<110, pad->128)
#define PW1F_OFF 32768    // [256][32]     W1 feat rows, k-map [feat_i(15) 0 feat_j(15) 0]
#define PW2_OFF  40960    // [8][256][32]
#define PWR_OFF  106496   // [8][256][32]
#define PWH_OFF  172032   // [8][16][32]   [mean_w | lstd_w | pad]
#define WS_TOTAL 176128

__global__ __launch_bounds__(256) void prep_weights(
    const float* __restrict__ w1, const float* __restrict__ w2,
    const float* __restrict__ wr, const float* __restrict__ wm,
    const float* __restrict__ wl, _Float16* __restrict__ ws)
{
  int idx = blockIdx.x * 256 + threadIdx.x;
  if (idx < 32768) {            // pw1b
    int kk = idx & 31, n = (idx >> 5) & 255, kt = idx >> 13;
    int k = kt * 32 + kk;
    ws[idx] = (k < 110) ? (_Float16)w1[k * 256 + n] : (_Float16)0.f;
  } else if (idx < 40960) {     // pw1f
    int t = idx - 32768;
    int kk = t & 31, n = t >> 5;
    _Float16 v = (_Float16)0.f;
    if (kk < 15)                  v = (_Float16)w1[(113 + kk) * 256 + n];
    else if (kk >= 16 && kk < 31) v = (_Float16)w1[(131 + (kk - 16)) * 256 + n];
    ws[idx] = v;
  } else if (idx < 106496) {    // pw2
    int t = idx - 40960;
    int kk = t & 31, n = (t >> 5) & 255, kt = t >> 13;
    ws[idx] = (_Float16)w2[(kt * 32 + kk) * 256 + n];
  } else if (idx < 172032) {    // pwr
    int t = idx - 106496;
    int kk = t & 31, n = (t >> 5) & 255, kt = t >> 13;
    ws[idx] = (_Float16)wr[(kt * 32 + kk) * 256 + n];
  } else if (idx < WS_TOTAL) {  // pwh
    int t = idx - 172032;
    int kk = t & 31, n = (t >> 5) & 15, kt = t >> 9;
    int k = kt * 32 + kk;
    _Float16 v = (_Float16)0.f;
    if (n < 4) v = (_Float16)wm[k * 4 + n];
    else if (n < 8) v = (_Float16)wl[k * 4 + (n - 4)];
    ws[PWH_OFF + t] = v;
  }
}

// R17. Occupancy law established over R13-R16: HW allocates TOTAL regs
// (arch + accum) in tiers {64,128,256}; 512-thread blocks need total <= 128
// for 2 blocks/CU. R13: 64+48=112 -> 2 blocks (but 64-tier arch forced 12MB
// spill). R15/R16: arch 80-84 + ~48-56 accum > 128 -> 256-tier -> 1 block,
// occ 23%, slow despite zero spill.
// R17 targets total ~120: R13 skeleton (u once, 2x3-perm phases, 6 barriers)
//  - g2 rt-SPLIT (not nt): acc[6]=24 accum; per-kt LDS a-reads stay 6 total
//    (nt-split had 12); only pw2 is re-streamed 2x (cheap L2 traffic).
//  - agg regs eliminated (-16): perm-sum accumulated as fp16 RMW directly
//    into Bb (dead after U; each lane RMWs only its own cells; fp16 partial
//    agg verified safe in R15, absmax unchanged at 0.03125).
// g2 live: acc24+u16+transients ~ 80 arch + 40 accum ~ 120 <= 128.
__global__ __launch_bounds__(512) void actor_fused(
    const float* __restrict__ obs, const float* __restrict__ lemb,
    const float* __restrict__ w1, const _Float16* __restrict__ ws,
    const float* __restrict__ b1, const float* __restrict__ b2,
    const float* __restrict__ br, const float* __restrict__ bm,
    const float* __restrict__ bl, float* __restrict__ out)
{
  __shared__ __align__(16) _Float16 H1[6 * 16 * 256]; // 48 KB: 6 tiles (pp*2+rt); tiles 0,1 later r
  __shared__ __align__(16) _Float16 Bb[32 * 256];     // 16 KB: base (K=128), then agg accumulator
  __shared__ __align__(16) _Float16 Os[3 * 32 * 16];  //  3 KB: compact obj tiles
  __shared__ __align__(16) float    Bsf[6 * 256];     //  6 KB: fused per-perm biases (f32)

  const _Float16* __restrict__ pw1b = ws + PW1B_OFF;
  const _Float16* __restrict__ pw1f = ws + PW1F_OFF;
  const _Float16* __restrict__ pw2  = ws + PW2_OFF;
  const _Float16* __restrict__ pwr  = ws + PWR_OFF;
  const _Float16* __restrict__ pwh  = ws + PWH_OFF;

  const int tid  = threadIdx.x;
  const int wave = tid >> 6;        // 0..7
  const int lane = tid & 63;
  const int q    = lane >> 4;
  const int l16  = lane & 15;
  const int colbase = wave * 32;    // this wave's 32 output cols
  const int rowbase = blockIdx.x * TB;

  const int c0_0 = colbase + q * 4;        // start col of this lane's 4-col pack, nt=0
  const int c0_1 = colbase + 16 + q * 4;   // nt=1

  // ---- stage base (32 rows x K=128) -- wave-contiguous: lane i writes 8B at
  // chunk_base + i*8 within one 512B k-octet chunk -> conflict-free ----
  for (int idx = tid; idx < 1024; idx += 512) {
    int oct = idx >> 6;          // 0..15 (= k-octet)
    int r   = (idx >> 1) & 31;   // row
    int hf  = idx & 1;           // which 4-col half of the octet
    int c   = oct * 8 + hf * 4;
    float v0, v1, v2, v3;
    if (c + 3 < 100) {
      float4 f = *(const float4*)(lemb + (rowbase + r) * 100 + c);
      v0 = f.x; v1 = f.y; v2 = f.z; v3 = f.w;
    } else {
      const float* orow = obs + (rowbase + r) * 55;
      const float* lrow = lemb + (rowbase + r) * 100;
      float t[4];
      #pragma unroll
      for (int j = 0; j < 4; ++j) {
        int cc = c + j;
        t[j] = cc < 100 ? lrow[cc] : (cc < 110 ? orow[cc - 100] : 0.f);
      }
      v0 = t[0]; v1 = t[1]; v2 = t[2]; v3 = t[3];
    }
    half4v hv = {(_Float16)v0, (_Float16)v1, (_Float16)v2, (_Float16)v3};
    *(half4v*)&Bb[(oct * 32 + r) * 8 + hf * 4] = hv;
  }
  // ---- compact obj tiles: 3 obj x 2 k-octets x 32 rows, 8B per lane ----
  for (int idx = tid; idx < 384; idx += 512) {
    int o   = idx >> 7;          // 0..2
    int k4i = (idx >> 5) & 3;    // which 4-k group
    int r   = idx & 31;
    int k0  = k4i * 4;
    const float* frow = obs + (rowbase + r) * 55 + 10 + o * 15;
    float t[4];
    #pragma unroll
    for (int j = 0; j < 4; ++j) {
      int k = k0 + j;
      t[j] = (k < 15) ? frow[k] : 0.f;
    }
    half4v hv = {(_Float16)t[0], (_Float16)t[1], (_Float16)t[2], (_Float16)t[3]};
    *(half4v*)&Os[o * 512 + ((k0 >> 3) * 32 + r) * 8 + (k0 & 7)] = hv;
  }
  // ---- fused per-perm biases (f32): b1 + W1[onehot_i row] + W1[onehot_j row] ----
  for (int idx = tid; idx < 1536; idx += 512) {
    int p = idx >> 8, c = idx & 255;
    int oi = p >> 1, oj = (1161 >> (2 * p)) & 3;
    Bsf[idx] = b1[c] + w1[(110 + oi) * 256 + c] + w1[(128 + oj) * 256 + c];
  }
  __syncthreads();  // B1

  const fx4 zero4 = {0.f, 0.f, 0.f, 0.f};

  // ---- U = (base @ W1base)^T tiles (K=128), computed ONCE, held in regs ----
  fx4 u[4];  // [rt*2+nt]
  u[0] = zero4; u[1] = zero4; u[2] = zero4; u[3] = zero4;
  #pragma unroll
  for (int kt = 0; kt < 4; ++kt) {
    half8 a0 = *(const half8*)&Bb[((kt * 4 + q) * 32 + l16) * 8];
    half8 a1 = *(const half8*)&Bb[((kt * 4 + q) * 32 + 16 + l16) * 8];
    #pragma unroll
    for (int nt = 0; nt < 2; ++nt) {
      half8 b = *(const half8*)&pw1b[(kt * 256 + colbase + nt * 16 + l16) * 32 + q * 8];
      u[nt]     = __builtin_amdgcn_mfma_f32_16x16x32_f16(b, a0, u[nt], 0, 0, 0);
      u[2 + nt] = __builtin_amdgcn_mfma_f32_16x16x32_f16(b, a1, u[2 + nt], 0, 0, 0);
    }
  }
  // no barrier: Bb not rewritten until the first g2 epilogue, which is after
  // B2 -- by then every wave is past its own U reads.

  // ---- GEMM1 group: h1_p = relu(U + F_p @ W1f + bias_p), perms {3g..3g+2} ----
  // swapped D: lane holds row l16 (batch), cols c0..c0+3 -> packed b64 store
  auto g1_group = [&](int g) {
    half8 b1f0 = *(const half8*)&pw1f[(colbase + l16) * 32 + q * 8];
    half8 b1f1 = *(const half8*)&pw1f[(colbase + 16 + l16) * 32 + q * 8];
    #pragma unroll
    for (int pp = 0; pp < 3; ++pp) {
      const int p = g * 3 + pp;
      const int oi = p >> 1, oj = (1161 >> (2 * p)) & 3;
      const int o = (q < 2) ? oi : oj;   // quads 0,1 -> feat_i; 2,3 -> feat_j
      #pragma unroll
      for (int rt = 0; rt < 2; ++rt) {
        half8 af = *(const half8*)&Os[o * 512 + ((q & 1) * 32 + rt * 16 + l16) * 8];
        #pragma unroll
        for (int nt = 0; nt < 2; ++nt) {
          fx4 t = __builtin_amdgcn_mfma_f32_16x16x32_f16(nt ? b1f1 : b1f0, af,
                                                         u[rt * 2 + nt], 0, 0, 0);
          const int c0 = nt ? c0_1 : c0_0;
          fx4 bs = *(const fx4*)&Bsf[p * 256 + c0];
          half4v hv = {(_Float16)fmaxf(t[0] + bs[0], 0.f),
                       (_Float16)fmaxf(t[1] + bs[1], 0.f),
                       (_Float16)fmaxf(t[2] + bs[2], 0.f),
                       (_Float16)fmaxf(t[3] + bs[3], 0.f)};
          *(half4v*)&H1[(pp * 2 + rt) * 4096 + ((c0 >> 3) * 16 + l16) * 8 + (c0 & 7)] = hv;
        }
      }
    }
  };

  // ---- GEMM2 group: rt-SPLIT -- two passes over row-halves, acc[6]=24 accum.
  // Per kt per pass: 2 global bb + 3 LDS a reads; total a-reads/kt = 6 (same
  // as R13). Perm-sum goes straight into Bb as fp16 RMW (first=plain store).
  auto g2_group = [&](bool first) {
    #pragma unroll
    for (int rt = 0; rt < 2; ++rt) {
      fx4 bv0 = *(const fx4*)&b2[c0_0];
      fx4 bv1 = *(const fx4*)&b2[c0_1];
      fx4 acc[6];  // [pp*2+nt]
      #pragma unroll
      for (int i = 0; i < 6; ++i) acc[i] = (i & 1) ? bv1 : bv0;
      #pragma unroll 2
      for (int kt = 0; kt < 8; ++kt) {
        half8 bb0 = *(const half8*)&pw2[(kt * 256 + colbase + l16) * 32 + q * 8];
        half8 bb1 = *(const half8*)&pw2[(kt * 256 + colbase + 16 + l16) * 32 + q * 8];
        #pragma unroll
        for (int pp = 0; pp < 3; ++pp) {
          half8 a = *(const half8*)&H1[(pp * 2 + rt) * 4096 + ((kt * 4 + q) * 16 + l16) * 8];
          acc[pp * 2]     = __builtin_amdgcn_mfma_f32_16x16x32_f16(bb0, a, acc[pp * 2], 0, 0, 0);
          acc[pp * 2 + 1] = __builtin_amdgcn_mfma_f32_16x16x32_f16(bb1, a, acc[pp * 2 + 1], 0, 0, 0);
        }
      }
      // epilogue: sum relu across the 3 perms, RMW into Bb (lane-owned cells)
      #pragma unroll
      for (int nt = 0; nt < 2; ++nt) {
        const int c0 = nt ? c0_1 : c0_0;
        fx4 s = zero4;
        #pragma unroll
        for (int pp = 0; pp < 3; ++pp)
          #pragma unroll
          for (int rr = 0; rr < 4; ++rr)
            s[rr] += fmaxf(acc[pp * 2 + nt][rr], 0.f);
        _Float16* cell = &Bb[((c0 >> 3) * 32 + rt * 16 + l16) * 8 + (c0 & 7)];
        if (!first) {
          half4v old = *(half4v*)cell;
          #pragma unroll
          for (int rr = 0; rr < 4; ++rr) s[rr] += (float)old[rr];
        }
        half4v hv = {(_Float16)s[0], (_Float16)s[1], (_Float16)s[2], (_Float16)s[3]};
        *(half4v*)cell = hv;
      }
    }
  };

  g1_group(0);
  __syncthreads();  // B2: h1 perms 0-2 ready (and all U reads of Bb done)
  g2_group(true);
  __syncthreads();  // B3: all H1 reads of group 0 done
  g1_group(1);
  __syncthreads();  // B4: h1 perms 3-5 ready
  g2_group(false);
  __syncthreads();  // B5: agg complete in Bb; all H1 reads done

  // ---- GEMM3: r = relu(agg @ rho + br), M=32, K=256; r -> H1 tiles 0,1 ----
  fx4 acc3[4];  // [rt*2+nt]
  {
    fx4 brv0 = *(const fx4*)&br[c0_0];
    fx4 brv1 = *(const fx4*)&br[c0_1];
    acc3[0] = brv0; acc3[1] = brv1; acc3[2] = brv0; acc3[3] = brv1;
  }
  #pragma unroll 2
  for (int kt = 0; kt < 8; ++kt) {
    half8 a0 = *(const half8*)&Bb[((kt * 4 + q) * 32 + l16) * 8];
    half8 a1 = *(const half8*)&Bb[((kt * 4 + q) * 32 + 16 + l16) * 8];
    half8 b0 = *(const half8*)&pwr[(kt * 256 + colbase + l16) * 32 + q * 8];
    half8 b1h = *(const half8*)&pwr[(kt * 256 + colbase + 16 + l16) * 32 + q * 8];
    acc3[0] = __builtin_amdgcn_mfma_f32_16x16x32_f16(b0,  a0, acc3[0], 0, 0, 0);
    acc3[1] = __builtin_amdgcn_mfma_f32_16x16x32_f16(b1h, a0, acc3[1], 0, 0, 0);
    acc3[2] = __builtin_amdgcn_mfma_f32_16x16x32_f16(b0,  a1, acc3[2], 0, 0, 0);
    acc3[3] = __builtin_amdgcn_mfma_f32_16x16x32_f16(b1h, a1, acc3[3], 0, 0, 0);
  }
  #pragma unroll
  for (int rt = 0; rt < 2; ++rt)
    #pragma unroll
    for (int nt = 0; nt < 2; ++nt) {
      const int c0 = nt ? c0_1 : c0_0;
      fx4 t = acc3[rt * 2 + nt];
      half4v hv = {(_Float16)fmaxf(t[0], 0.f), (_Float16)fmaxf(t[1], 0.f),
                   (_Float16)fmaxf(t[2], 0.f), (_Float16)fmaxf(t[3], 0.f)};
      *(half4v*)&H1[rt * 4096 + ((c0 >> 3) * 16 + l16) * 8 + (c0 & 7)] = hv;
    }
  __syncthreads();  // B6: r ready

  // ---- heads: waves 0,1 (one row-half each); swapped D -> float4 stores ----
  if (wave < 2) {
    fx4 a4 = zero4;
    #pragma unroll 2
    for (int kt = 0; kt < 8; ++kt) {
      half8 rfrag = *(const half8*)&H1[wave * 4096 + ((kt * 4 + q) * 16 + l16) * 8];
      half8 wfrag = *(const half8*)&pwh[(kt * 16 + l16) * 32 + q * 8];
      a4 = __builtin_amdgcn_mfma_f32_16x16x32_f16(wfrag, rfrag, a4, 0, 0, 0);
    }
    const int row = rowbase + wave * 16 + l16;
    if (q == 0) {            // head cols 0..3 = mean
      fx4 bm4 = *(const fx4*)bm;
      fx4 o = {a4[0] + bm4[0], a4[1] + bm4[1], a4[2] + bm4[2], a4[3] + bm4[3]};
      *(fx4*)&out[row * 4] = o;
    } else if (q == 1) {     // head cols 4..7 = log_std (clipped)
      fx4 bl4 = *(const fx4*)bl;
      fx4 o;
      #pragma unroll
      for (int rr = 0; rr < 4; ++rr) {
        float v = a4[rr] + bl4[rr];
        o[rr] = v < -20.f ? -20.f : (v > 2.f ? 2.f : v);
      }
      *(fx4*)&out[BATCH * 4 + row * 4] = o;
    }
  }
}

extern "C" void kernel_launch(void* const* d_in, const int* in_sizes, int n_in,
                              void* d_out, int out_size, void* d_ws, size_t ws_size,
                              hipStream_t stream) {
  const float* obs  = (const float*)d_in[0];
  const float* lemb = (const float*)d_in[1];
  const float* w1   = (const float*)d_in[2];
  const float* b1   = (const float*)d_in[3];
  const float* w2   = (const float*)d_in[4];
  const float* b2   = (const float*)d_in[5];
  const float* wr   = (const float*)d_in[6];
  const float* br   = (const float*)d_in[7];
  const float* wm   = (const float*)d_in[8];
  const float* bm   = (const float*)d_in[9];
  const float* wl   = (const float*)d_in[10];
  const float* bl   = (const float*)d_in[11];
  float* out = (float*)d_out;
  _Float16* ws = (_Float16*)d_ws;

  hipLaunchKernelGGL(prep_weights, dim3(WS_TOTAL / 256), dim3(256), 0, stream,
                     w1, w2, wr, wm, wl, ws);
  hipLaunchKernelGGL(actor_fused, dim3(BATCH / TB), dim3(512), 0, stream,
                     obs, lemb, w1, (const _Float16*)ws, b1, b2, br, bm, bl, out);
}